// Round 5
// baseline (69.968 us; speedup 1.0000x reference)
//
#include <hip/hip_runtime.h>

#define NVOX 129600            // 60*36*60
#define NCH  512
#define NPIX 19200             // 120*160
#define IMW  160
#define VB   256               // voxels per gather block
#define CB   32                // channels per gather block
#define LSTR 260               // LDS row stride (floats): mult-of-4 (b128 align)
#define NQ   (NCH / CB)        // 16 channel chunks
#define NVB  ((NVOX + VB - 1) / VB)   // 507 voxel blocks (last has 64)

typedef float vfloat4 __attribute__((ext_vector_type(4)));  // NT-store-able

__device__ __forceinline__ int project_voxel(
    int v, const float* __restrict__ pose, const float* __restrict__ origin,
    const float* __restrict__ camk, int flip)
{
    int gx = v / 2160;                 // 36*60
    int r  = v - gx * 2160;
    int gy = r / 60;
    int gz = r - gy * 60;
    float wx = gx * 0.08f + 0.04f + origin[0];
    float wy = gz * 0.08f + 0.04f + origin[1];
    float wz = gy * 0.08f + 0.04f + origin[2];
    float cx = pose[0]*wx + pose[1]*wy + pose[2]*wz  + pose[3];
    float cy = pose[4]*wx + pose[5]*wy + pose[6]*wz  + pose[7];
    float cz = pose[8]*wx + pose[9]*wy + pose[10]*wz + pose[11];
    float ix = camk[0]*cx + camk[1]*cy + camk[2]*cz;
    float iy = camk[3]*cx + camk[4]*cy + camk[5]*cz;
    float iz = camk[6]*cx + camk[7]*cy + camk[8]*cz;
    float u  = rintf(ix / iz);         // round half-to-even == jnp.round
    float vv = rintf(iy / iz);
    bool ok = (cz > 0.0f) && (u >= 0.0f) && (u < 640.0f)
                          && (vv >= 0.0f) && (vv < 480.0f);
    if (!ok) return -1;
    float colf = flip ? (639.0f - u) : u;
    return ((((int)vv) >> 2) * IMW) + (((int)colf) >> 2);
}

// ---- pass 1: transpose x2d (512,19200) -> xT (19200,512), + projection ----
// Blocks with linear id < NVB also compute lin[] for 256 voxels each.
__global__ __launch_bounds__(256) void transpose_proj_kernel(
    const float* __restrict__ x2d, float* __restrict__ xT,
    int* __restrict__ lin,
    const float* __restrict__ pose, const float* __restrict__ origin,
    const float* __restrict__ camk, const int* __restrict__ fliplr)
{
    int bid = blockIdx.y * gridDim.x + blockIdx.x;
    int t   = threadIdx.x;
    if (bid < NVB) {                   // fused projection (ALU-only, hidden)
        int v = bid * 256 + t;
        if (v < NVOX)
            lin[v] = project_voxel(v, pose, origin, camk, fliplr[0]);
    }

    __shared__ float tile[64][65];
    int p0 = blockIdx.x * 64;          // pixel tile base
    int c0 = blockIdx.y * 64;          // channel tile base
    int a  = t & 15;                   // float4 slot
    int bq = t >> 4;                   // 0..15

    const float4* src4 = reinterpret_cast<const float4*>(x2d);
#pragma unroll
    for (int i = 0; i < 4; ++i) {
        int c = bq + i * 16;
        float4 v = src4[((size_t)(c0 + c) * NPIX + p0) / 4 + a];
        tile[a * 4 + 0][c] = v.x;
        tile[a * 4 + 1][c] = v.y;
        tile[a * 4 + 2][c] = v.z;
        tile[a * 4 + 3][c] = v.w;
    }
    __syncthreads();
    float4* dst4 = reinterpret_cast<float4*>(xT);
#pragma unroll
    for (int i = 0; i < 4; ++i) {
        int p = bq + i * 16;
        float4 v;
        v.x = tile[p][a * 4 + 0];
        v.y = tile[p][a * 4 + 1];
        v.z = tile[p][a * 4 + 2];
        v.w = tile[p][a * 4 + 3];
        dst4[((size_t)(p0 + p) * NCH + c0) / 4 + a] = v;
    }
}

// ---- pass 2: gather. block = 256 voxels x 32 channels, 512 threads ----
__global__ __launch_bounds__(512) void gather_kernel(
    const float* __restrict__ xT, const int* __restrict__ lin,
    float* __restrict__ out)
{
    __shared__ float lds[CB * LSTR];   // [channel][voxel], 33.3 KB

    int b  = blockIdx.x;
    int q  = b & (NQ - 1);             // channel chunk (inner -> xT reuse)
    int vb = b >> 4;
    int v0 = vb * VB;
    int c0 = q * CB;
    int nv = min(VB, NVOX - v0);       // 256, or 64 for the tail block
    int t  = threadIdx.x;

    // load: iter i covers rows i*64 + (t>>3); lane channel-quad (t&7)*4
    const float4* xT4 = reinterpret_cast<const float4*>(xT);
#pragma unroll
    for (int i = 0; i < 4; ++i) {
        int r  = i * 64 + (t >> 3);
        int c4 = (t & 7) * 4;
        if (r < nv) {
            int l = lin[v0 + r];       // 8 lanes same addr (broadcast)
            if (l >= 0) {
                float4 val = xT4[((size_t)l * NCH + c0 + c4) >> 2];
                lds[(c4 + 0) * LSTR + r] = val.x;
                lds[(c4 + 1) * LSTR + r] = val.y;
                lds[(c4 + 2) * LSTR + r] = val.z;
                lds[(c4 + 3) * LSTR + r] = val.w;
            }
        }
    }
    __syncthreads();

    // store: wave wv, lane = voxel quad; vfloat4 NT stores (1KB/wave-instr)
    int wv = t >> 6, lane = t & 63;
    int vq = lane * 4;
    int4 lv = make_int4(-1, -1, -1, -1);
    if (vq < nv)
        lv = reinterpret_cast<const int4*>(lin + v0)[lane];
#pragma unroll
    for (int i = 0; i < 4; ++i) {
        int cc = i * 8 + wv;
        if (vq < nv) {
            const float* row = &lds[cc * LSTR + vq];   // 16B-aligned
            float4 d = *reinterpret_cast<const float4*>(row);
            vfloat4 o;
            o.x = (lv.x >= 0) ? d.x : 0.0f;
            o.y = (lv.y >= 0) ? d.y : 0.0f;
            o.z = (lv.z >= 0) ? d.z : 0.0f;
            o.w = (lv.w >= 0) ? d.w : 0.0f;
            __builtin_nontemporal_store(o, reinterpret_cast<vfloat4*>(
                out + (size_t)(c0 + cc) * NVOX + v0 + vq));
        }
    }
}

// ---------- fallback (round-1 kernel) if d_ws is too small ----------
__global__ __launch_bounds__(256) void fused_kernel(
    const float* __restrict__ x2d, const float* __restrict__ pose,
    const float* __restrict__ origin, const float* __restrict__ camk,
    const int* __restrict__ fliplr, float* __restrict__ out)
{
    long tid = (long)blockIdx.x * blockDim.x + threadIdx.x;
    int g  = (int)(tid % 32400);
    int cg = (int)(tid / 32400);
    if (cg >= 64) return;
    int v0 = g * 4;
    int linv[4];
#pragma unroll
    for (int i = 0; i < 4; ++i)
        linv[i] = project_voxel(v0 + i, pose, origin, camk, fliplr[0]);
    int ch0 = cg * 8;
#pragma unroll
    for (int cc = 0; cc < 8; ++cc) {
        int ch = ch0 + cc;
        const float* s = x2d + (size_t)ch * NPIX;
        float4 o;
        o.x = (linv[0] >= 0) ? s[linv[0]] : 0.0f;
        o.y = (linv[1] >= 0) ? s[linv[1]] : 0.0f;
        o.z = (linv[2] >= 0) ? s[linv[2]] : 0.0f;
        o.w = (linv[3] >= 0) ? s[linv[3]] : 0.0f;
        *reinterpret_cast<float4*>(out + (size_t)ch * NVOX + v0) = o;
    }
}

extern "C" void kernel_launch(void* const* d_in, const int* in_sizes, int n_in,
                              void* d_out, int out_size, void* d_ws, size_t ws_size,
                              hipStream_t stream) {
    const float* x2d    = (const float*)d_in[0];
    const float* pose   = (const float*)d_in[1];
    const float* origin = (const float*)d_in[2];
    const float* camk   = (const float*)d_in[3];
    const int*   flip   = (const int*)d_in[6];
    float*       out    = (float*)d_out;

    const size_t xT_bytes  = (size_t)NPIX * NCH * sizeof(float);   // 39.32 MB
    const size_t lin_bytes = (size_t)NVB * VB * sizeof(int);       // 519 KB (padded)
    if (ws_size >= xT_bytes + lin_bytes) {
        float* xT   = (float*)d_ws;
        int*   linb = (int*)((char*)d_ws + xT_bytes);
        transpose_proj_kernel<<<dim3(NPIX / 64, NCH / 64), dim3(256), 0, stream>>>(
            x2d, xT, linb, pose, origin, camk, flip);
        gather_kernel<<<dim3(NVB * NQ), dim3(512), 0, stream>>>(xT, linb, out);
    } else {
        fused_kernel<<<dim3(8100), dim3(256), 0, stream>>>(
            x2d, pose, origin, camk, flip, out);
    }
}

// Round 6
// 65.517 us; speedup vs baseline: 1.0679x; 1.0679x over previous
//
#include <hip/hip_runtime.h>

#define NVOX 129600             // 60*36*60
#define NCH  512
#define IMH  120                // 480/4
#define IMW  160                // 640/4
#define NPIX (IMH * IMW)        // 19200
#define LSTRIDE 161             // padded LDS row stride (floats): row -> bank+1
#define PLANE_LDS (IMH * LSTRIDE)   // 19320 floats = 77280 B (2 blocks/CU)

typedef float vfloat4 __attribute__((ext_vector_type(4)));  // NT-store-able

__device__ __forceinline__ int project_voxel_pad(
    int v, const float* __restrict__ pose, const float* __restrict__ origin,
    const float* __restrict__ camk, int flip)
{
    int gx = v / 2160;                 // 36*60
    int r  = v - gx * 2160;
    int gy = r / 60;
    int gz = r - gy * 60;
    float wx = gx * 0.08f + 0.04f + origin[0];
    float wy = gz * 0.08f + 0.04f + origin[1];
    float wz = gy * 0.08f + 0.04f + origin[2];
    float cx = pose[0]*wx + pose[1]*wy + pose[2]*wz  + pose[3];
    float cy = pose[4]*wx + pose[5]*wy + pose[6]*wz  + pose[7];
    float cz = pose[8]*wx + pose[9]*wy + pose[10]*wz + pose[11];
    float ix = camk[0]*cx + camk[1]*cy + camk[2]*cz;
    float iy = camk[3]*cx + camk[4]*cy + camk[5]*cz;
    float iz = camk[6]*cx + camk[7]*cy + camk[8]*cz;
    float u  = rintf(ix / iz);         // round half-to-even == jnp.round
    float vv = rintf(iy / iz);
    bool ok = (cz > 0.0f) && (u >= 0.0f) && (u < 640.0f)
                          && (vv >= 0.0f) && (vv < 480.0f);
    if (!ok) return -1;
    float colf = flip ? (639.0f - u) : u;
    // padded LDS index: (row/4)*161 + (col/4)
    return (((int)vv) >> 2) * LSTRIDE + (((int)colf) >> 2);
}

// ---- pass 0: projection -> lin_pad[NVOX] (padded LDS index or -1) ----
__global__ __launch_bounds__(256) void proj_kernel(
    int* __restrict__ lin,
    const float* __restrict__ pose, const float* __restrict__ origin,
    const float* __restrict__ camk, const int* __restrict__ fliplr)
{
    int v = blockIdx.x * 256 + threadIdx.x;
    if (v < NVOX)
        lin[v] = project_voxel_pad(v, pose, origin, camk, fliplr[0]);
}

// ---- pass 1: one block per channel; plane staged in LDS; coalesced out ----
__global__ __launch_bounds__(1024, 8) void chan_kernel(
    const float* __restrict__ x2d, const int* __restrict__ lin,
    float* __restrict__ out)
{
    __shared__ float plane[PLANE_LDS];          // 77.3 KB -> 2 blocks/CU
    int c = blockIdx.x;
    int t = threadIdx.x;

    // stage: coalesced read of this channel's 120x160 plane, pad-store
    const float4* src4 = reinterpret_cast<const float4*>(x2d)
                       + (size_t)c * (NPIX / 4);
#pragma unroll
    for (int i = 0; i < 5; ++i) {
        int p4 = i * 1024 + t;
        if (p4 < NPIX / 4) {
            float4 val = src4[p4];
            int p   = p4 * 4;
            int row = p / IMW;                  // const-div
            int col = p - row * IMW;            // float4 stays in-row (160%4==0)
            float* d = &plane[row * LSTRIDE + col];
            d[0] = val.x; d[1] = val.y; d[2] = val.z; d[3] = val.w;
        }
    }
    __syncthreads();

    // gather: lin_pad (L2-hot, coalesced int4) -> LDS reads -> NT float4 out
    const int4* lin4 = reinterpret_cast<const int4*>(lin);
    vfloat4* out4 = reinterpret_cast<vfloat4*>(out) + (size_t)c * (NVOX / 4);
#pragma unroll 4
    for (int i = 0; i < 32; ++i) {
        int g = i * 1024 + t;
        if (g < NVOX / 4) {
            int4 l = lin4[g];
            vfloat4 o;
            o.x = (l.x >= 0) ? plane[l.x] : 0.0f;
            o.y = (l.y >= 0) ? plane[l.y] : 0.0f;
            o.z = (l.z >= 0) ? plane[l.z] : 0.0f;
            o.w = (l.w >= 0) ? plane[l.w] : 0.0f;
            __builtin_nontemporal_store(o, &out4[g]);
        }
    }
}

// ---------- fallback if d_ws is too small (round-1 kernel, ws-free) ----------
__global__ __launch_bounds__(256) void fused_kernel(
    const float* __restrict__ x2d, const float* __restrict__ pose,
    const float* __restrict__ origin, const float* __restrict__ camk,
    const int* __restrict__ fliplr, float* __restrict__ out)
{
    long tid = (long)blockIdx.x * blockDim.x + threadIdx.x;
    int g  = (int)(tid % 32400);
    int cg = (int)(tid / 32400);
    if (cg >= 64) return;
    int v0 = g * 4;
    int linv[4];
#pragma unroll
    for (int i = 0; i < 4; ++i) {
        int lp = project_voxel_pad(v0 + i, pose, origin, camk, fliplr[0]);
        // un-pad back to compact pixel index
        linv[i] = (lp >= 0) ? (lp - lp / LSTRIDE) : -1;
    }
    int ch0 = cg * 8;
#pragma unroll
    for (int cc = 0; cc < 8; ++cc) {
        int ch = ch0 + cc;
        const float* s = x2d + (size_t)ch * NPIX;
        float4 o;
        o.x = (linv[0] >= 0) ? s[linv[0]] : 0.0f;
        o.y = (linv[1] >= 0) ? s[linv[1]] : 0.0f;
        o.z = (linv[2] >= 0) ? s[linv[2]] : 0.0f;
        o.w = (linv[3] >= 0) ? s[linv[3]] : 0.0f;
        *reinterpret_cast<float4*>(out + (size_t)ch * NVOX + v0) = o;
    }
}

extern "C" void kernel_launch(void* const* d_in, const int* in_sizes, int n_in,
                              void* d_out, int out_size, void* d_ws, size_t ws_size,
                              hipStream_t stream) {
    const float* x2d    = (const float*)d_in[0];
    const float* pose   = (const float*)d_in[1];
    const float* origin = (const float*)d_in[2];
    const float* camk   = (const float*)d_in[3];
    const int*   flip   = (const int*)d_in[6];
    float*       out    = (float*)d_out;

    const size_t lin_bytes = (size_t)NVOX * sizeof(int);   // 518.4 KB
    if (ws_size >= lin_bytes) {
        int* linb = (int*)d_ws;
        proj_kernel<<<dim3((NVOX + 255) / 256), dim3(256), 0, stream>>>(
            linb, pose, origin, camk, flip);
        chan_kernel<<<dim3(NCH), dim3(1024), 0, stream>>>(x2d, linb, out);
    } else {
        fused_kernel<<<dim3(8100), dim3(256), 0, stream>>>(
            x2d, pose, origin, camk, flip, out);
    }
}

// Round 7
// 63.661 us; speedup vs baseline: 1.0991x; 1.0291x over previous
//
#include <hip/hip_runtime.h>

#define NVOX 129600             // 60*36*60
#define NCH  512
#define IMH  120                // 480/4
#define IMW  160                // 640/4
#define NPIX (IMH * IMW)        // 19200
#define LSTR2 162               // float2 row stride (even -> 16B-aligned b128)
#define PLANE2 (IMH * LSTR2)    // 19440 float2 = 155,520 B LDS (1 block/CU)

typedef float vfloat4 __attribute__((ext_vector_type(4)));
typedef float vfloat2 __attribute__((ext_vector_type(2)));
typedef unsigned short vushort4 __attribute__((ext_vector_type(4)));

// row*stride + col of the downsampled pixel, or -1 if outside frustum
__device__ __forceinline__ int project_voxel_s(
    int v, const float* __restrict__ pose, const float* __restrict__ origin,
    const float* __restrict__ camk, int flip, int stride)
{
    int gx = v / 2160;                 // 36*60
    int r  = v - gx * 2160;
    int gy = r / 60;
    int gz = r - gy * 60;
    float wx = gx * 0.08f + 0.04f + origin[0];
    float wy = gz * 0.08f + 0.04f + origin[1];
    float wz = gy * 0.08f + 0.04f + origin[2];
    float cx = pose[0]*wx + pose[1]*wy + pose[2]*wz  + pose[3];
    float cy = pose[4]*wx + pose[5]*wy + pose[6]*wz  + pose[7];
    float cz = pose[8]*wx + pose[9]*wy + pose[10]*wz + pose[11];
    float ix = camk[0]*cx + camk[1]*cy + camk[2]*cz;
    float iy = camk[3]*cx + camk[4]*cy + camk[5]*cz;
    float iz = camk[6]*cx + camk[7]*cy + camk[8]*cz;
    float u  = rintf(ix / iz);         // round half-to-even == jnp.round
    float vv = rintf(iy / iz);
    bool ok = (cz > 0.0f) && (u >= 0.0f) && (u < 640.0f)
                          && (vv >= 0.0f) && (vv < 480.0f);
    if (!ok) return -1;
    float colf = flip ? (639.0f - u) : u;
    return (((int)vv) >> 2) * stride + (((int)colf) >> 2);
}

// ---- pass 0: projection -> lin16[NVOX] (padded float2-idx or 0xFFFF) ----
__global__ __launch_bounds__(256) void proj_kernel(
    unsigned short* __restrict__ lin16,
    const float* __restrict__ pose, const float* __restrict__ origin,
    const float* __restrict__ camk, const int* __restrict__ fliplr)
{
    int v = blockIdx.x * 256 + threadIdx.x;
    if (v < NVOX) {
        int l = project_voxel_s(v, pose, origin, camk, fliplr[0], LSTR2);
        lin16[v] = (l >= 0) ? (unsigned short)l : (unsigned short)0xFFFF;
    }
}

// ---- pass 1: one block per CHANNEL PAIR; interleaved float2 plane in LDS ----
__global__ __launch_bounds__(1024, 1) void chan2_kernel(
    const float* __restrict__ x2d, const unsigned short* __restrict__ lin16,
    float* __restrict__ out)
{
    __shared__ vfloat2 plane[PLANE2];   // 155.5 KB: {chA[p], chB[p]} per pixel
    int b = blockIdx.x;                 // 0..255
    int t = threadIdx.x;
    int c0 = b * 2;

    // stage: coalesced NT float4 reads of both planes, b128 interleaved writes
    const vfloat4* srcA = reinterpret_cast<const vfloat4*>(
        x2d + (size_t)c0 * NPIX);
    const vfloat4* srcB = reinterpret_cast<const vfloat4*>(
        x2d + (size_t)(c0 + 1) * NPIX);
#pragma unroll
    for (int i = 0; i < 5; ++i) {
        int j = i * 1024 + t;           // float4 index within plane (0..4799)
        if (j < NPIX / 4) {
            vfloat4 a  = __builtin_nontemporal_load(&srcA[j]);
            vfloat4 b4 = __builtin_nontemporal_load(&srcB[j]);
            int p   = j * 4;
            int row = p / IMW;
            int col = p - row * IMW;    // float4 stays in-row (160%4==0)
            int idx = row * LSTR2 + col;            // even -> 16B aligned
            vfloat4 w0 = {a.x, b4.x, a.y, b4.y};
            vfloat4 w1 = {a.z, b4.z, a.w, b4.w};
            *reinterpret_cast<vfloat4*>(&plane[idx])     = w0;
            *reinterpret_cast<vfloat4*>(&plane[idx + 2]) = w1;
        }
    }
    __syncthreads();

    // gather: 4 voxels x 2 channels per iter: 8B idx load + 4 ds_read_b64
    vfloat4* outA = reinterpret_cast<vfloat4*>(out + (size_t)c0 * NVOX);
    vfloat4* outB = reinterpret_cast<vfloat4*>(out + (size_t)(c0 + 1) * NVOX);
#pragma unroll 4
    for (int i = 0; i < 32; ++i) {
        int g = i * 1024 + t;
        if (g < NVOX / 4) {
            vushort4 l4 = *reinterpret_cast<const vushort4*>(lin16 + g * 4);
            bool m0 = l4.x != 0xFFFFu, m1 = l4.y != 0xFFFFu,
                 m2 = l4.z != 0xFFFFu, m3 = l4.w != 0xFFFFu;
            vfloat2 v0 = plane[m0 ? l4.x : 0];
            vfloat2 v1 = plane[m1 ? l4.y : 0];
            vfloat2 v2 = plane[m2 ? l4.z : 0];
            vfloat2 v3 = plane[m3 ? l4.w : 0];
            vfloat4 oA = { m0 ? v0.x : 0.0f, m1 ? v1.x : 0.0f,
                           m2 ? v2.x : 0.0f, m3 ? v3.x : 0.0f };
            vfloat4 oB = { m0 ? v0.y : 0.0f, m1 ? v1.y : 0.0f,
                           m2 ? v2.y : 0.0f, m3 ? v3.y : 0.0f };
            __builtin_nontemporal_store(oA, &outA[g]);
            __builtin_nontemporal_store(oB, &outB[g]);
        }
    }
}

// ---------- fallback if d_ws is too small (ws-free, round-1 style) ----------
__global__ __launch_bounds__(256) void fused_kernel(
    const float* __restrict__ x2d, const float* __restrict__ pose,
    const float* __restrict__ origin, const float* __restrict__ camk,
    const int* __restrict__ fliplr, float* __restrict__ out)
{
    long tid = (long)blockIdx.x * blockDim.x + threadIdx.x;
    int g  = (int)(tid % 32400);
    int cg = (int)(tid / 32400);
    if (cg >= 64) return;
    int v0 = g * 4;
    int linv[4];
#pragma unroll
    for (int i = 0; i < 4; ++i)
        linv[i] = project_voxel_s(v0 + i, pose, origin, camk, fliplr[0], IMW);
    int ch0 = cg * 8;
#pragma unroll
    for (int cc = 0; cc < 8; ++cc) {
        int ch = ch0 + cc;
        const float* s = x2d + (size_t)ch * NPIX;
        float4 o;
        o.x = (linv[0] >= 0) ? s[linv[0]] : 0.0f;
        o.y = (linv[1] >= 0) ? s[linv[1]] : 0.0f;
        o.z = (linv[2] >= 0) ? s[linv[2]] : 0.0f;
        o.w = (linv[3] >= 0) ? s[linv[3]] : 0.0f;
        *reinterpret_cast<float4*>(out + (size_t)ch * NVOX + v0) = o;
    }
}

extern "C" void kernel_launch(void* const* d_in, const int* in_sizes, int n_in,
                              void* d_out, int out_size, void* d_ws, size_t ws_size,
                              hipStream_t stream) {
    const float* x2d    = (const float*)d_in[0];
    const float* pose   = (const float*)d_in[1];
    const float* origin = (const float*)d_in[2];
    const float* camk   = (const float*)d_in[3];
    const int*   flip   = (const int*)d_in[6];
    float*       out    = (float*)d_out;

    const size_t lin_bytes = (size_t)NVOX * sizeof(unsigned short); // 259.2 KB
    if (ws_size >= lin_bytes) {
        unsigned short* lin16 = (unsigned short*)d_ws;
        proj_kernel<<<dim3((NVOX + 255) / 256), dim3(256), 0, stream>>>(
            lin16, pose, origin, camk, flip);
        chan2_kernel<<<dim3(NCH / 2), dim3(1024), 0, stream>>>(
            x2d, lin16, out);
    } else {
        fused_kernel<<<dim3(8100), dim3(256), 0, stream>>>(
            x2d, pose, origin, camk, flip, out);
    }
}